// Round 1
// baseline (284.708 us; speedup 1.0000x reference)
//
#include <hip/hip_runtime.h>
#include <hip/hip_bf16.h>
#include <stdint.h>

#define DEVINLINE __device__ __forceinline__

typedef __attribute__((ext_vector_type(4))) float f32x4;
typedef __attribute__((ext_vector_type(8))) short bf16x8;

DEVINLINE unsigned short f2bf(float f) {
    union { float f; uint32_t u; } v; v.f = f;
    uint32_t u = v.u;
    uint32_t rounding = 0x7FFFu + ((u >> 16) & 1u);
    u += rounding;
    return (unsigned short)(u >> 16);
}

DEVINLINE float bf2f(unsigned short h) {
    union { uint32_t u; float f; } v; v.u = ((uint32_t)h) << 16;
    return v.f;
}

// ---------------- fp32 -> bf16 elementwise convert ----------------
__global__ void cvt_f32_bf16(const float* __restrict__ in,
                             unsigned short* __restrict__ out, int n) {
    int i = (blockIdx.x * blockDim.x + threadIdx.x) * 4;
    int stride = gridDim.x * blockDim.x * 4;
    for (; i < n; i += stride) {
        float4 v = *reinterpret_cast<const float4*>(in + i);
        ushort4 o;
        o.x = f2bf(v.x); o.y = f2bf(v.y); o.z = f2bf(v.z); o.w = f2bf(v.w);
        *reinterpret_cast<ushort4*>(out + i) = o;
    }
}

// ---------------- fp32 [R][C] -> bf16 [C][R] transpose ----------------
__global__ void transpose_cvt(const float* __restrict__ in,
                              unsigned short* __restrict__ out,
                              int R, int Ccols) {
    __shared__ float tile[32][33];
    int c0 = blockIdx.x * 32, r0 = blockIdx.y * 32;
    int tx = threadIdx.x, ty = threadIdx.y; // 32 x 8
    #pragma unroll
    for (int j = 0; j < 32; j += 8)
        tile[ty + j][tx] = in[(size_t)(r0 + ty + j) * Ccols + c0 + tx];
    __syncthreads();
    #pragma unroll
    for (int j = 0; j < 32; j += 8)
        out[(size_t)(c0 + ty + j) * R + r0 + tx] = f2bf(tile[tx][ty + j]);
}

// ---------------- bf16 MFMA GEMM: A[M][K] x Bt[N][K] + bias -> C[M][N] ----------------
// m97 structure: 128x128 tile, BK=32, 4 waves, global_load_lds width 16.
template <bool OUT_BF16>
__launch_bounds__(256)
__global__ void gemm_bt(const unsigned short* __restrict__ A,
                        const unsigned short* __restrict__ Bt,
                        const float* __restrict__ bias,
                        void* __restrict__ Cout,
                        int M, int N, int K) {
    constexpr int BK = 32;
    __shared__ unsigned short As[128 * BK]; // [m][k]
    __shared__ unsigned short Bs[128 * BK]; // [n][k]

    int t = threadIdx.x;
    int wid = t >> 6, lane = t & 63;
    int bm = blockIdx.x * 128;
    int bn = blockIdx.y * 128;

    // staging addresses: thread t covers 16B at flat byte t*16 (+ j*4096)
    int srow = t >> 2;              // 0..63
    int scol = (t & 3) * 8;         // element offset
    const unsigned short* gA = A + (size_t)(bm + srow) * K + scol;
    const unsigned short* gB = Bt + (size_t)(bn + srow) * K + scol;
    char* ldsA = (char*)As + wid * 1024;
    char* ldsB = (char*)Bs + wid * 1024;

    int wr = wid >> 1, wc = wid & 1;
    int fr = lane & 15;   // frag row (A) / col (B)
    int fq = lane >> 4;   // k-subblock
    const unsigned short* aBase = As + (wr * 64 + fr) * BK + fq * 8;
    const unsigned short* bBase = Bs + (wc * 64 + fr) * BK + fq * 8;

    f32x4 acc[4][4] = {};

    for (int kt = 0; kt < K; kt += BK) {
        __syncthreads();
        {
            const unsigned short* a0 = gA + kt;
            const unsigned short* b0 = gB + kt;
            __builtin_amdgcn_global_load_lds(
                (const __attribute__((address_space(1))) void*)a0,
                (__attribute__((address_space(3))) void*)ldsA, 16, 0, 0);
            __builtin_amdgcn_global_load_lds(
                (const __attribute__((address_space(1))) void*)(a0 + (size_t)64 * K),
                (__attribute__((address_space(3))) void*)(ldsA + 4096), 16, 0, 0);
            __builtin_amdgcn_global_load_lds(
                (const __attribute__((address_space(1))) void*)b0,
                (__attribute__((address_space(3))) void*)ldsB, 16, 0, 0);
            __builtin_amdgcn_global_load_lds(
                (const __attribute__((address_space(1))) void*)(b0 + (size_t)64 * K),
                (__attribute__((address_space(3))) void*)(ldsB + 4096), 16, 0, 0);
        }
        __syncthreads();

        bf16x8 af[4], bfv[4];
        #pragma unroll
        for (int i = 0; i < 4; ++i) {
            af[i]  = *reinterpret_cast<const bf16x8*>(aBase + i * 16 * BK);
            bfv[i] = *reinterpret_cast<const bf16x8*>(bBase + i * 16 * BK);
        }
        #pragma unroll
        for (int mi = 0; mi < 4; ++mi)
            #pragma unroll
            for (int ni = 0; ni < 4; ++ni)
                acc[mi][ni] = __builtin_amdgcn_mfma_f32_16x16x32_bf16(
                    af[mi], bfv[ni], acc[mi][ni], 0, 0, 0);
    }

    // epilogue: add bias, store
    #pragma unroll
    for (int mi = 0; mi < 4; ++mi) {
        #pragma unroll
        for (int ni = 0; ni < 4; ++ni) {
            int col = bn + wc * 64 + ni * 16 + fr;
            float bv = bias[col];
            #pragma unroll
            for (int r = 0; r < 4; ++r) {
                int row = bm + wr * 64 + mi * 16 + fq * 4 + r;
                float val = acc[mi][ni][r] + bv;
                if (OUT_BF16)
                    ((unsigned short*)Cout)[(size_t)row * N + col] = f2bf(val);
                else
                    ((float*)Cout)[(size_t)row * N + col] = val;
            }
        }
    }
}

// ---------------- per-position head-mixing attention ----------------
// qkv[pos][h*192 + j]: j<64 q, 64<=j<128 k, 128<=j<192 v.
// attn[h][t] = (q[h].k[t]) / 32; softmax over t; out[pos][h*64+d] = sum_t p*v[t][d]
__global__ __launch_bounds__(64)
void attn_kernel(const unsigned short* __restrict__ qkv,
                 unsigned short* __restrict__ out) {
    __shared__ float sq[16][65], sk[16][65], sv[16][65];
    __shared__ float sp[16][17];
    int pos = blockIdx.x;
    int t = threadIdx.x;
    const unsigned short* rowp = qkv + (size_t)pos * 3072;

    #pragma unroll
    for (int j = 0; j < 6; ++j) {
        int f = (j * 64 + t) * 8;
        ushort4 v0 = *reinterpret_cast<const ushort4*>(rowp + f);
        ushort4 v1 = *reinterpret_cast<const ushort4*>(rowp + f + 4);
        float vals[8] = {bf2f(v0.x), bf2f(v0.y), bf2f(v0.z), bf2f(v0.w),
                         bf2f(v1.x), bf2f(v1.y), bf2f(v1.z), bf2f(v1.w)};
        int h = f / 192;
        int r = f % 192;
        float* dst = (r < 64) ? &sq[h][r] : (r < 128) ? &sk[h][r - 64] : &sv[h][r - 128];
        #pragma unroll
        for (int i = 0; i < 8; ++i) dst[i] = vals[i];
    }
    __syncthreads();

    int h = t >> 2;
    int tq = t & 3;
    float s[4];
    #pragma unroll
    for (int jj = 0; jj < 4; ++jj) {
        int tt = tq * 4 + jj;
        float acc = 0.f;
        for (int d = 0; d < 64; ++d) acc += sq[h][d] * sk[tt][d];
        s[jj] = acc * 0.03125f;
    }
    float m = fmaxf(fmaxf(s[0], s[1]), fmaxf(s[2], s[3]));
    m = fmaxf(m, __shfl_xor(m, 1));
    m = fmaxf(m, __shfl_xor(m, 2));
    float e[4], sum = 0.f;
    #pragma unroll
    for (int jj = 0; jj < 4; ++jj) { e[jj] = __expf(s[jj] - m); sum += e[jj]; }
    sum += __shfl_xor(sum, 1);
    sum += __shfl_xor(sum, 2);
    float inv = 1.0f / sum;
    #pragma unroll
    for (int jj = 0; jj < 4; ++jj) sp[h][tq * 4 + jj] = e[jj] * inv;
    __syncthreads();

    int dbase = tq * 16;
    float o[16] = {};
    for (int tt = 0; tt < 16; ++tt) {
        float p = sp[h][tt];
        #pragma unroll
        for (int dd = 0; dd < 16; ++dd) o[dd] += p * sv[tt][dbase + dd];
    }
    unsigned short ob[16];
    #pragma unroll
    for (int dd = 0; dd < 16; ++dd) ob[dd] = f2bf(o[dd]);
    ushort4* po = (ushort4*)(out + (size_t)pos * 1024 + h * 64 + dbase);
    #pragma unroll
    for (int i = 0; i < 4; ++i) {
        ushort4 w = { ob[i*4+0], ob[i*4+1], ob[i*4+2], ob[i*4+3] };
        po[i] = w;
    }
}

extern "C" void kernel_launch(void* const* d_in, const int* in_sizes, int n_in,
                              void* d_out, int out_size, void* d_ws, size_t ws_size,
                              hipStream_t stream) {
    const float* x     = (const float*)d_in[0];
    const float* w_qkv = (const float*)d_in[1];
    const float* b_qkv = (const float*)d_in[2];
    const float* w_o   = (const float*)d_in[3];
    const float* b_o   = (const float*)d_in[4];
    float* out = (float*)d_out;

    const int C = 1024, E = 1024;
    const int M = 16 * 1024;      // B*S = 16384
    const int N1 = 3 * E;         // 3072

    char* ws = (char*)d_ws;
    unsigned short* xb    = (unsigned short*)ws;            // M*C bf16
    unsigned short* wqkvT = xb    + (size_t)M * C;          // N1*C
    unsigned short* qkv   = wqkvT + (size_t)N1 * C;         // M*N1
    unsigned short* woT   = qkv   + (size_t)M * N1;         // E*E
    unsigned short* aout  = woT   + (size_t)E * E;          // M*E

    cvt_f32_bf16<<<2048, 256, 0, stream>>>(x, xb, M * C);
    dim3 tb(32, 8);
    transpose_cvt<<<dim3(N1 / 32, C / 32), tb, 0, stream>>>(w_qkv, wqkvT, C, N1);
    transpose_cvt<<<dim3(E / 32, E / 32), tb, 0, stream>>>(w_o, woT, E, E);

    gemm_bt<true><<<dim3(M / 128, N1 / 128), 256, 0, stream>>>(xb, wqkvT, b_qkv, qkv, M, N1, C);
    attn_kernel<<<M, 64, 0, stream>>>(qkv, aout);
    gemm_bt<false><<<dim3(M / 128, E / 128), 256, 0, stream>>>(aout, woT, b_o, out, M, E, E);
}

// Round 2
// 234.497 us; speedup vs baseline: 1.2141x; 1.2141x over previous
//
#include <hip/hip_runtime.h>
#include <hip/hip_bf16.h>
#include <stdint.h>

#define DEVINLINE __device__ __forceinline__

typedef __attribute__((ext_vector_type(4))) float f32x4;
typedef __attribute__((ext_vector_type(8))) short bf16x8;

DEVINLINE unsigned short f2bf(float f) {
    union { float f; uint32_t u; } v; v.f = f;
    uint32_t u = v.u;
    uint32_t rounding = 0x7FFFu + ((u >> 16) & 1u);
    u += rounding;
    return (unsigned short)(u >> 16);
}

DEVINLINE float bf2f(unsigned short h) {
    union { uint32_t u; float f; } v; v.u = ((uint32_t)h) << 16;
    return v.f;
}

// ---------------- fp32 -> bf16 elementwise convert ----------------
__global__ void cvt_f32_bf16(const float* __restrict__ in,
                             unsigned short* __restrict__ out, int n) {
    int i = (blockIdx.x * blockDim.x + threadIdx.x) * 4;
    int stride = gridDim.x * blockDim.x * 4;
    for (; i < n; i += stride) {
        float4 v = *reinterpret_cast<const float4*>(in + i);
        ushort4 o;
        o.x = f2bf(v.x); o.y = f2bf(v.y); o.z = f2bf(v.z); o.w = f2bf(v.w);
        *reinterpret_cast<ushort4*>(out + i) = o;
    }
}

// ---------------- fp32 [R][C] -> bf16 [C][R] transpose ----------------
__global__ void transpose_cvt(const float* __restrict__ in,
                              unsigned short* __restrict__ out,
                              int R, int Ccols) {
    __shared__ float tile[32][33];
    int c0 = blockIdx.x * 32, r0 = blockIdx.y * 32;
    int tx = threadIdx.x, ty = threadIdx.y; // 32 x 8
    #pragma unroll
    for (int j = 0; j < 32; j += 8)
        tile[ty + j][tx] = in[(size_t)(r0 + ty + j) * Ccols + c0 + tx];
    __syncthreads();
    #pragma unroll
    for (int j = 0; j < 32; j += 8)
        out[(size_t)(c0 + ty + j) * R + r0 + tx] = f2bf(tile[tx][ty + j]);
}

// ============ 256x256 8-phase bf16 GEMM: A[M][K] x Bt[N][K] + bias -> C[M][N] ============
// 8 waves (2M x 4N), BK=64, 128 KiB LDS double-buffered as 4 half-tiles
// (A0,A1,B0,B1). XOR swizzle (col8 ^= row&7) applied via pre-swizzled global
// source + swizzled ds_read. Counted vmcnt at K-tile boundaries only.

// stage one half-tile (128 rows x 64 cols bf16) = 2 global_load_lds x 8 waves
#define STAGE_HALF(bufsel, regionOff, srcBase, row0, tileIdx)                          \
    do {                                                                               \
        const unsigned short* _s = (srcBase) + (size_t)(row0) * K + (size_t)(tileIdx) * 64; \
        unsigned short* _d = (unsigned short*)lds + ((bufsel) << 15) + (regionOff) + wid * 512; \
        __builtin_amdgcn_global_load_lds(                                              \
            (const __attribute__((address_space(1))) void*)_s,                         \
            (__attribute__((address_space(3))) void*)_d, 16, 0, 0);                    \
        __builtin_amdgcn_global_load_lds(                                              \
            (const __attribute__((address_space(1))) void*)(_s + (size_t)64 * K),      \
            (__attribute__((address_space(3))) void*)(_d + 4096), 16, 0, 0);           \
    } while (0)

#define LDA(mbase)                                                                     \
    do {                                                                               \
        _Pragma("unroll")                                                              \
        for (int _i = 0; _i < 4; ++_i) {                                               \
            int _ro = bufOff + ((wr * 128 + ((mbase) + _i) * 16 + fr) << 6);           \
            aR[_i][0] = *(const bf16x8*)(lds + _ro + colS0);                           \
            aR[_i][1] = *(const bf16x8*)(lds + _ro + colS1);                           \
        }                                                                              \
    } while (0)

#define LDB(nh)                                                                        \
    do {                                                                               \
        _Pragma("unroll")                                                              \
        for (int _j = 0; _j < 2; ++_j) {                                               \
            int _ro = bufOff + 16384 + ((wc * 64 + ((nh) * 2 + _j) * 16 + fr) << 6);   \
            bR[nh][_j][0] = *(const bf16x8*)(lds + _ro + colS0);                       \
            bR[nh][_j][1] = *(const bf16x8*)(lds + _ro + colS1);                       \
        }                                                                              \
    } while (0)

#define MMA_Q(mh, nh)                                                                  \
    do {                                                                               \
        __builtin_amdgcn_s_setprio(1);                                                 \
        _Pragma("unroll")                                                              \
        for (int _i = 0; _i < 4; ++_i) {                                               \
            _Pragma("unroll")                                                          \
            for (int _j = 0; _j < 2; ++_j) {                                           \
                acc[(mh) * 4 + _i][(nh) * 2 + _j] =                                    \
                    __builtin_amdgcn_mfma_f32_16x16x32_bf16(                           \
                        aR[_i][0], bR[nh][_j][0], acc[(mh) * 4 + _i][(nh) * 2 + _j], 0, 0, 0); \
                acc[(mh) * 4 + _i][(nh) * 2 + _j] =                                    \
                    __builtin_amdgcn_mfma_f32_16x16x32_bf16(                           \
                        aR[_i][1], bR[nh][_j][1], acc[(mh) * 4 + _i][(nh) * 2 + _j], 0, 0, 0); \
            }                                                                          \
        }                                                                              \
        __builtin_amdgcn_s_setprio(0);                                                 \
    } while (0)

#define BAR() asm volatile("s_barrier" ::: "memory")

template <bool OUT_BF16>
__launch_bounds__(512, 2)
__global__ void gemm256(const unsigned short* __restrict__ A,
                        const unsigned short* __restrict__ Bt,
                        const float* __restrict__ bias,
                        void* __restrict__ Cout,
                        int M, int N, int K, int NTN) {
    __shared__ unsigned short lds[65536]; // 128 KiB: 2 buf x (A 256x64 + B 256x64)
    const int NT = K >> 6;

    int t = threadIdx.x;
    int wid = t >> 6, lane = t & 63;
    int wr = wid >> 2, wc = wid & 3;
    int fr = lane & 15, fq = lane >> 4;

    // XCD-aware block swizzle (grid % 8 == 0 for our shapes)
    int nwg = gridDim.x;
    int bid = blockIdx.x;
    int cpx = nwg >> 3;
    int swz = (bid & 7) * cpx + (bid >> 3);
    int tm = swz / NTN, tn = swz % NTN;
    int bm = tm * 256, bn = tn * 256;

    // staging source (per-lane, pre-swizzled column)
    int rowl = t >> 3;                       // 0..63
    int col8 = t & 7;                        // 16B slot
    int swzcol = (col8 ^ (rowl & 7)) << 3;   // element offset, inverse-swizzled
    const unsigned short* aSrc = A + (size_t)(bm + rowl) * K + swzcol;
    const unsigned short* bSrc = Bt + (size_t)(bn + rowl) * K + swzcol;

    // ds_read swizzled column offsets (row&7 == fr&7 for all our rows)
    int swzm = (fr & 7) << 3;
    int colS0 = ((fq << 3)) ^ swzm;          // ks=0
    int colS1 = (32 | (fq << 3)) ^ swzm;     // ks=1

    f32x4 acc[8][4] = {};
    bf16x8 aR[4][2];
    bf16x8 bR[2][2][2];

    // regions (ushort offsets): A0=0, A1=8192, B0=16384, B1=24576
    // prologue: tile0 fully + tile1 {B0,A0}
    STAGE_HALF(0, 16384, bSrc, 0, 0);
    STAGE_HALF(0, 0, aSrc, 0, 0);
    STAGE_HALF(0, 24576, bSrc, 128, 0);
    STAGE_HALF(0, 8192, aSrc, 128, 0);
    if (NT > 1) {
        STAGE_HALF(1, 16384, bSrc, 0, 1);
        STAGE_HALF(1, 0, aSrc, 0, 1);
        asm volatile("s_waitcnt vmcnt(4)" ::: "memory");
    } else {
        asm volatile("s_waitcnt vmcnt(0)" ::: "memory");
    }
    BAR();

    for (int tt = 0; tt < NT; ++tt) {
        int cur = tt & 1;
        int nxt = cur ^ 1;
        int bufOff = cur << 15;

        // ---- p0: read A[mh=0], B[nh=0]; stage B1(t+1) ----
        LDA(0);
        LDB(0);
        if (tt + 1 < NT) STAGE_HALF(nxt, 24576, bSrc, 128, tt + 1);
        BAR();
        MMA_Q(0, 0);
        BAR();

        // ---- p1: read B[nh=1]; stage A1(t+1) ----
        LDB(1);
        if (tt + 1 < NT) STAGE_HALF(nxt, 8192, aSrc, 128, tt + 1);
        BAR();
        MMA_Q(0, 1);
        BAR();

        // ---- p2: read A[mh=1]; stage B0(t+2) ----
        LDA(4);
        if (tt + 2 < NT) STAGE_HALF(cur, 16384, bSrc, 0, tt + 2);
        BAR();
        MMA_Q(1, 1);
        BAR();

        // ---- p3: stage A0(t+2); reuse aR + bR[0] ----
        if (tt + 2 < NT) STAGE_HALF(cur, 0, aSrc, 0, tt + 2);
        BAR();
        MMA_Q(1, 0);
        // K-tile boundary: everything for tile t+1 must have landed.
        if (tt + 2 < NT) asm volatile("s_waitcnt vmcnt(4)" ::: "memory");
        else             asm volatile("s_waitcnt vmcnt(0)" ::: "memory");
        BAR();
    }

    // epilogue: bias + store
    #pragma unroll
    for (int m = 0; m < 8; ++m) {
        #pragma unroll
        for (int n = 0; n < 4; ++n) {
            int col = bn + wc * 64 + n * 16 + fr;
            float bv = bias[col];
            #pragma unroll
            for (int r = 0; r < 4; ++r) {
                int row = bm + wr * 128 + m * 16 + fq * 4 + r;
                float v = acc[m][n][r] + bv;
                if (OUT_BF16)
                    ((unsigned short*)Cout)[(size_t)row * N + col] = f2bf(v);
                else
                    ((float*)Cout)[(size_t)row * N + col] = v;
            }
        }
    }
}

// ---------------- per-position head-mixing attention ----------------
__global__ __launch_bounds__(64)
void attn_kernel(const unsigned short* __restrict__ qkv,
                 unsigned short* __restrict__ out) {
    __shared__ float sq[16][65], sk[16][65], sv[16][65];
    __shared__ float sp[16][17];
    int pos = blockIdx.x;
    int t = threadIdx.x;
    const unsigned short* rowp = qkv + (size_t)pos * 3072;

    #pragma unroll
    for (int j = 0; j < 6; ++j) {
        int f = (j * 64 + t) * 8;
        ushort4 v0 = *reinterpret_cast<const ushort4*>(rowp + f);
        ushort4 v1 = *reinterpret_cast<const ushort4*>(rowp + f + 4);
        float vals[8] = {bf2f(v0.x), bf2f(v0.y), bf2f(v0.z), bf2f(v0.w),
                         bf2f(v1.x), bf2f(v1.y), bf2f(v1.z), bf2f(v1.w)};
        int h = f / 192;
        int r = f % 192;
        float* dst = (r < 64) ? &sq[h][r] : (r < 128) ? &sk[h][r - 64] : &sv[h][r - 128];
        #pragma unroll
        for (int i = 0; i < 8; ++i) dst[i] = vals[i];
    }
    __syncthreads();

    int h = t >> 2;
    int tq = t & 3;
    float s[4];
    #pragma unroll
    for (int jj = 0; jj < 4; ++jj) {
        int tt = tq * 4 + jj;
        float acc = 0.f;
        for (int d = 0; d < 64; ++d) acc += sq[h][d] * sk[tt][d];
        s[jj] = acc * 0.03125f;
    }
    float m = fmaxf(fmaxf(s[0], s[1]), fmaxf(s[2], s[3]));
    m = fmaxf(m, __shfl_xor(m, 1));
    m = fmaxf(m, __shfl_xor(m, 2));
    float e[4], sum = 0.f;
    #pragma unroll
    for (int jj = 0; jj < 4; ++jj) { e[jj] = __expf(s[jj] - m); sum += e[jj]; }
    sum += __shfl_xor(sum, 1);
    sum += __shfl_xor(sum, 2);
    float inv = 1.0f / sum;
    #pragma unroll
    for (int jj = 0; jj < 4; ++jj) sp[h][tq * 4 + jj] = e[jj] * inv;
    __syncthreads();

    int dbase = tq * 16;
    float o[16] = {};
    for (int tt = 0; tt < 16; ++tt) {
        float p = sp[h][tt];
        #pragma unroll
        for (int dd = 0; dd < 16; ++dd) o[dd] += p * sv[tt][dbase + dd];
    }
    unsigned short ob[16];
    #pragma unroll
    for (int dd = 0; dd < 16; ++dd) ob[dd] = f2bf(o[dd]);
    ushort4* po = (ushort4*)(out + (size_t)pos * 1024 + h * 64 + dbase);
    #pragma unroll
    for (int i = 0; i < 4; ++i) {
        ushort4 w = { ob[i*4+0], ob[i*4+1], ob[i*4+2], ob[i*4+3] };
        po[i] = w;
    }
}

extern "C" void kernel_launch(void* const* d_in, const int* in_sizes, int n_in,
                              void* d_out, int out_size, void* d_ws, size_t ws_size,
                              hipStream_t stream) {
    const float* x     = (const float*)d_in[0];
    const float* w_qkv = (const float*)d_in[1];
    const float* b_qkv = (const float*)d_in[2];
    const float* w_o   = (const float*)d_in[3];
    const float* b_o   = (const float*)d_in[4];
    float* out = (float*)d_out;

    const int C = 1024, E = 1024;
    const int M = 16 * 1024;      // B*S = 16384
    const int N1 = 3 * E;         // 3072

    char* ws = (char*)d_ws;
    unsigned short* xb    = (unsigned short*)ws;            // M*C bf16
    unsigned short* wqkvT = xb    + (size_t)M * C;          // N1*C
    unsigned short* qkv   = wqkvT + (size_t)N1 * C;         // M*N1
    unsigned short* woT   = qkv   + (size_t)M * N1;         // E*E
    unsigned short* aout  = woT   + (size_t)E * E;          // M*E

    cvt_f32_bf16<<<2048, 256, 0, stream>>>(x, xb, M * C);
    dim3 tb(32, 8);
    transpose_cvt<<<dim3(N1 / 32, C / 32), tb, 0, stream>>>(w_qkv, wqkvT, C, N1);
    transpose_cvt<<<dim3(E / 32, E / 32), tb, 0, stream>>>(w_o, woT, E, E);

    // QKV: M=16384, N=3072, K=1024 -> grid 64*12=768 blocks
    gemm256<true><<<dim3((M / 256) * (N1 / 256)), 512, 0, stream>>>(
        xb, wqkvT, b_qkv, qkv, M, N1, C, N1 / 256);
    attn_kernel<<<M, 64, 0, stream>>>(qkv, aout);
    // O-proj: M=16384, N=1024 -> grid 64*4=256 blocks
    gemm256<false><<<dim3((M / 256) * (E / 256)), 512, 0, stream>>>(
        aout, woT, b_o, out, M, E, E, E / 256);
}

// Round 5
// 225.783 us; speedup vs baseline: 1.2610x; 1.0386x over previous
//
#include <hip/hip_runtime.h>
#include <hip/hip_bf16.h>
#include <stdint.h>

#define DEVINLINE __device__ __forceinline__

typedef __attribute__((ext_vector_type(4))) float f32x4;
typedef __attribute__((ext_vector_type(8))) short bf16x8;

DEVINLINE unsigned short f2bf(float f) {
    union { float f; uint32_t u; } v; v.f = f;
    uint32_t u = v.u;
    uint32_t rounding = 0x7FFFu + ((u >> 16) & 1u);
    u += rounding;
    return (unsigned short)(u >> 16);
}

DEVINLINE float bf2f(unsigned short h) {
    union { uint32_t u; float f; } v; v.u = ((uint32_t)h) << 16;
    return v.f;
}

// ---------------- fp32 -> bf16 elementwise convert ----------------
__global__ void cvt_f32_bf16(const float* __restrict__ in,
                             unsigned short* __restrict__ out, int n) {
    int i = (blockIdx.x * blockDim.x + threadIdx.x) * 4;
    int stride = gridDim.x * blockDim.x * 4;
    for (; i < n; i += stride) {
        float4 v = *reinterpret_cast<const float4*>(in + i);
        ushort4 o;
        o.x = f2bf(v.x); o.y = f2bf(v.y); o.z = f2bf(v.z); o.w = f2bf(v.w);
        *reinterpret_cast<ushort4*>(out + i) = o;
    }
}

// ---------------- fp32 [R][C] -> bf16 [C][R] transpose ----------------
__global__ void transpose_cvt(const float* __restrict__ in,
                              unsigned short* __restrict__ out,
                              int R, int Ccols) {
    __shared__ float tile[32][33];
    int c0 = blockIdx.x * 32, r0 = blockIdx.y * 32;
    int tx = threadIdx.x, ty = threadIdx.y; // 32 x 8
    #pragma unroll
    for (int j = 0; j < 32; j += 8)
        tile[ty + j][tx] = in[(size_t)(r0 + ty + j) * Ccols + c0 + tx];
    __syncthreads();
    #pragma unroll
    for (int j = 0; j < 32; j += 8)
        out[(size_t)(c0 + ty + j) * R + r0 + tx] = f2bf(tile[tx][ty + j]);
}

// ============ 256x256 bf16 GEMM, read-ahead pipelined (race-audited) ============
// 8 waves (2M x 4N), BK=64, 128 KiB LDS double-buffered.
// Phase p = { MMA(quadrant p); ds_reads for phase p+1; [stages]; [vmcnt]; s_barrier }.
// Quadrants (0,0),(0,1),(1,0),(1,1); reads 4/8/4/8; stages B(tt+2)@p2, A(tt+2)@p3.
// Invariants: stage only >=1 barrier after last reader's drain; read "next" only
// >=1 barrier after the vmcnt that forces its landing. vmcnt(4) at p1/p2 ends.

#define GLD(srcp, dstp) __builtin_amdgcn_global_load_lds( \
    (const __attribute__((address_space(1))) void*)(srcp), \
    (__attribute__((address_space(3))) void*)(dstp), 16, 0, 0)

// stage one half-tile (128 rows x 64 cols bf16): 2 loads x 8 waves
#define STAGE(P, regionUS, srcBase, row0, kkE) do { \
    const unsigned short* _s = (srcBase) + (size_t)(row0) * K + (kkE); \
    unsigned short* _d = lds + (P) * 32768 + (regionUS) + wid * 512; \
    GLD(_s, _d); GLD(_s + (size_t)64 * K, _d + 4096); } while (0)

#define RD_A(dst, AS0, AS1, h) do { _Pragma("unroll") \
    for (int _i = 0; _i < 4; ++_i) { \
        dst[_i][0] = *(const bf16x8*)((AS0) + ((h) * 8192 + _i * 2048)); \
        dst[_i][1] = *(const bf16x8*)((AS1) + ((h) * 8192 + _i * 2048)); } } while (0)

#define RD_B(dst, BS0, BS1, nh) do { _Pragma("unroll") \
    for (int _j = 0; _j < 2; ++_j) { \
        dst[_j][0] = *(const bf16x8*)((BS0) + ((nh) * 4096 + _j * 2048)); \
        dst[_j][1] = *(const bf16x8*)((BS1) + ((nh) * 4096 + _j * 2048)); } } while (0)

#define MMA(aX, bY, mh, nh) do { \
    __builtin_amdgcn_s_setprio(1); \
    _Pragma("unroll") for (int _i = 0; _i < 4; ++_i) { \
    _Pragma("unroll") for (int _j = 0; _j < 2; ++_j) { \
        acc[(mh)*4+_i][(nh)*2+_j] = __builtin_amdgcn_mfma_f32_16x16x32_bf16( \
            aX[_i][0], bY[_j][0], acc[(mh)*4+_i][(nh)*2+_j], 0, 0, 0); \
        acc[(mh)*4+_i][(nh)*2+_j] = __builtin_amdgcn_mfma_f32_16x16x32_bf16( \
            aX[_i][1], bY[_j][1], acc[(mh)*4+_i][(nh)*2+_j], 0, 0, 0); } } \
    __builtin_amdgcn_s_setprio(0); } while (0)

#define VM4 asm volatile("s_waitcnt vmcnt(4)" ::: "memory")
#define BAR() asm volatile("s_barrier" ::: "memory")

// One K-tile, parity-static LDS addresses. kk = clamped stage source column (elems).
// p0: MMA(0,0); rd bB(cur,nh1);                       BAR
// p1: MMA(0,1); rd aB(cur,h1);                  VM4;  BAR   (forces B(tt+1))
// p2: MMA(1,0); rd bA(nxt,nh0); stage B(tt+2);  VM4;  BAR   (forces A(tt+1))
// p3: MMA(1,1); rd aA(nxt,h0);  stage A(tt+2);        BAR
#define KTILE(AS0c, AS1c, BS0c, BS1c, AS0n, AS1n, BS0n, BS1n, Pc, kk) do { \
    MMA(aA, bA, 0, 0); \
    RD_B(bB, BS0c, BS1c, 1); \
    BAR(); \
    MMA(aA, bB, 0, 1); \
    RD_A(aB, AS0c, AS1c, 1); \
    VM4; BAR(); \
    MMA(aB, bA, 1, 0); \
    RD_B(bA, BS0n, BS1n, 0); \
    STAGE(Pc, 16384, bSrc, 0,   kk); \
    STAGE(Pc, 24576, bSrc, 128, kk); \
    VM4; BAR(); \
    MMA(aB, bB, 1, 1); \
    RD_A(aA, AS0n, AS1n, 0); \
    STAGE(Pc, 0,     aSrc, 0,   kk); \
    STAGE(Pc, 8192,  aSrc, 128, kk); \
    BAR(); } while (0)

template <bool OUT_BF16>
__launch_bounds__(512, 2)
__global__ void gemm256(const unsigned short* __restrict__ A,
                        const unsigned short* __restrict__ Bt,
                        const float* __restrict__ bias,
                        void* __restrict__ Cout,
                        int M, int N, int K, int NTN) {
    __shared__ unsigned short lds[65536]; // 128 KiB: 2 buf x (A 256x64 + B 256x64)
    const int NT = K >> 6;                // K-tiles (even, >= 2)

    int t = threadIdx.x;
    int wid = t >> 6, lane = t & 63;
    int wr = wid >> 2, wc = wid & 3;
    int fr = lane & 15, fq = lane >> 4;

    // XCD-aware block swizzle (grid % 8 == 0)
    int nwg = gridDim.x, bid = blockIdx.x;
    int cpx = nwg >> 3;
    int swz = (bid & 7) * cpx + (bid >> 3);
    int tm = swz / NTN, tn = swz % NTN;
    int bm = tm * 256, bn = tn * 256;

    // staging source (per-lane, pre-swizzled 16B slot)
    int rowl = t >> 3, col8 = t & 7;
    int swzcol = (col8 ^ (rowl & 7)) << 3;
    const unsigned short* aSrc = A + (size_t)(bm + rowl) * K + swzcol;
    const unsigned short* bSrc = Bt + (size_t)(bn + rowl) * K + swzcol;

    // ds_read swizzled base pointers (row&7 == fr&7 for all fragment rows)
    int swzm = (fr & 7) << 3;
    int colS0 = (fq << 3) ^ swzm;
    int colS1 = (32 | (fq << 3)) ^ swzm;

    char* ldsb = (char*)lds;
    char* A00 = ldsb + ((wr * 128 + fr) << 7) + 2 * colS0;
    char* A10 = ldsb + ((wr * 128 + fr) << 7) + 2 * colS1;
    char* B00 = ldsb + ((256 + wc * 64 + fr) << 7) + 2 * colS0;
    char* B10 = ldsb + ((256 + wc * 64 + fr) << 7) + 2 * colS1;
    char* A01 = A00 + 65536; char* A11 = A10 + 65536;
    char* B01 = B00 + 65536; char* B11 = B10 + 65536;

    f32x4 acc[8][4] = {};
    bf16x8 aA[4][2], aB[4][2], bA[2][2], bB[2][2];

    // ---- prologue: 16 loads = tiles 0 and 1, order A(0),B(0),B(1),A(1) ----
    STAGE(0, 0,     aSrc, 0,   0);   // A0(0)
    STAGE(0, 8192,  aSrc, 128, 0);   // A1(0)
    STAGE(0, 16384, bSrc, 0,   0);   // B0(0)
    STAGE(0, 24576, bSrc, 128, 0);   // B1(0)
    STAGE(1, 16384, bSrc, 0,   64);  // B0(1)
    STAGE(1, 24576, bSrc, 128, 64);  // B1(1)
    STAGE(1, 0,     aSrc, 0,   64);  // A0(1)
    STAGE(1, 8192,  aSrc, 128, 64);  // A1(1)
    asm volatile("s_waitcnt vmcnt(8)" ::: "memory"); // A(0),B(0) landed
    BAR();
    RD_A(aA, A00, A10, 0);   // A(0) h=0
    RD_B(bA, B00, B10, 0);   // B(0) nh=0

    for (int tau = 0; tau < NT; tau += 2) {
        int kkA = ((tau + 2 < NT) ? (tau + 2) : (NT - 1)) << 6;
        KTILE(A00, A10, B00, B10, A01, A11, B01, B11, 0, kkA);
        int kkB = ((tau + 3 < NT) ? (tau + 3) : (NT - 1)) << 6;
        KTILE(A01, A11, B01, B11, A00, A10, B00, B10, 1, kkB);
    }
    asm volatile("s_waitcnt vmcnt(0)" ::: "memory");

    // ---- epilogue: bias + store ----
    #pragma unroll
    for (int m = 0; m < 8; ++m) {
        #pragma unroll
        for (int n = 0; n < 4; ++n) {
            int col = bn + wc * 64 + n * 16 + fr;
            float bv = bias[col];
            #pragma unroll
            for (int r = 0; r < 4; ++r) {
                int row = bm + wr * 128 + m * 16 + fq * 4 + r;
                float v = acc[m][n][r] + bv;
                if (OUT_BF16)
                    ((unsigned short*)Cout)[(size_t)row * N + col] = f2bf(v);
                else
                    ((float*)Cout)[(size_t)row * N + col] = v;
            }
        }
    }
}

// ---------------- per-position head-mixing attention ----------------
__global__ __launch_bounds__(64)
void attn_kernel(const unsigned short* __restrict__ qkv,
                 unsigned short* __restrict__ out) {
    __shared__ float sq[16][65], sk[16][65], sv[16][65];
    __shared__ float sp[16][17];
    int pos = blockIdx.x;
    int t = threadIdx.x;
    const unsigned short* rowp = qkv + (size_t)pos * 3072;

    #pragma unroll
    for (int j = 0; j < 6; ++j) {
        int f = (j * 64 + t) * 8;
        ushort4 v0 = *reinterpret_cast<const ushort4*>(rowp + f);
        ushort4 v1 = *reinterpret_cast<const ushort4*>(rowp + f + 4);
        float vals[8] = {bf2f(v0.x), bf2f(v0.y), bf2f(v0.z), bf2f(v0.w),
                         bf2f(v1.x), bf2f(v1.y), bf2f(v1.z), bf2f(v1.w)};
        int h = f / 192;
        int r = f % 192;
        float* dst = (r < 64) ? &sq[h][r] : (r < 128) ? &sk[h][r - 64] : &sv[h][r - 128];
        #pragma unroll
        for (int i = 0; i < 8; ++i) dst[i] = vals[i];
    }
    __syncthreads();

    int h = t >> 2;
    int tq = t & 3;
    float s[4];
    #pragma unroll
    for (int jj = 0; jj < 4; ++jj) {
        int tt = tq * 4 + jj;
        float acc = 0.f;
        for (int d = 0; d < 64; ++d) acc += sq[h][d] * sk[tt][d];
        s[jj] = acc * 0.03125f;
    }
    float m = fmaxf(fmaxf(s[0], s[1]), fmaxf(s[2], s[3]));
    m = fmaxf(m, __shfl_xor(m, 1));
    m = fmaxf(m, __shfl_xor(m, 2));
    float e[4], sum = 0.f;
    #pragma unroll
    for (int jj = 0; jj < 4; ++jj) { e[jj] = __expf(s[jj] - m); sum += e[jj]; }
    sum += __shfl_xor(sum, 1);
    sum += __shfl_xor(sum, 2);
    float inv = 1.0f / sum;
    #pragma unroll
    for (int jj = 0; jj < 4; ++jj) sp[h][tq * 4 + jj] = e[jj] * inv;
    __syncthreads();

    int dbase = tq * 16;
    float o[16] = {};
    for (int tt = 0; tt < 16; ++tt) {
        float p = sp[h][tt];
        #pragma unroll
        for (int dd = 0; dd < 16; ++dd) o[dd] += p * sv[tt][dbase + dd];
    }
    unsigned short ob[16];
    #pragma unroll
    for (int dd = 0; dd < 16; ++dd) ob[dd] = f2bf(o[dd]);
    ushort4* po = (ushort4*)(out + (size_t)pos * 1024 + h * 64 + dbase);
    #pragma unroll
    for (int i = 0; i < 4; ++i) {
        ushort4 w = { ob[i*4+0], ob[i*4+1], ob[i*4+2], ob[i*4+3] };
        po[i] = w;
    }
}

extern "C" void kernel_launch(void* const* d_in, const int* in_sizes, int n_in,
                              void* d_out, int out_size, void* d_ws, size_t ws_size,
                              hipStream_t stream) {
    const float* x     = (const float*)d_in[0];
    const float* w_qkv = (const float*)d_in[1];
    const float* b_qkv = (const float*)d_in[2];
    const float* w_o   = (const float*)d_in[3];
    const float* b_o   = (const float*)d_in[4];
    float* out = (float*)d_out;

    const int C = 1024, E = 1024;
    const int M = 16 * 1024;      // B*S = 16384
    const int N1 = 3 * E;         // 3072

    char* ws = (char*)d_ws;
    unsigned short* xb    = (unsigned short*)ws;            // M*C bf16
    unsigned short* wqkvT = xb    + (size_t)M * C;          // N1*C
    unsigned short* qkv   = wqkvT + (size_t)N1 * C;         // M*N1
    unsigned short* woT   = qkv   + (size_t)M * N1;         // E*E
    unsigned short* aout  = woT   + (size_t)E * E;          // M*E

    cvt_f32_bf16<<<2048, 256, 0, stream>>>(x, xb, M * C);
    dim3 tb(32, 8);
    transpose_cvt<<<dim3(N1 / 32, C / 32), tb, 0, stream>>>(w_qkv, wqkvT, C, N1);
    transpose_cvt<<<dim3(E / 32, E / 32), tb, 0, stream>>>(w_o, woT, E, E);

    // QKV: M=16384, N=3072, K=1024 -> 768 blocks
    gemm256<true><<<dim3((M / 256) * (N1 / 256)), 512, 0, stream>>>(
        xb, wqkvT, b_qkv, qkv, M, N1, C, N1 / 256);
    attn_kernel<<<M, 64, 0, stream>>>(qkv, aout);
    // O-proj: M=16384, N=1024 -> 256 blocks
    gemm256<false><<<dim3((M / 256) * (E / 256)), 512, 0, stream>>>(
        aout, woT, b_o, out, M, E, E, E / 256);
}